// Round 1
// baseline (967.055 us; speedup 1.0000x reference)
//
#include <hip/hip_runtime.h>
#include <hip/hip_bf16.h>
#include <math.h>

#define T_LEN 512
#define B_SZ  256
#define I_SZ  300
#define H_SZ  64
#define G3    192   // 3H

// ---------------------------------------------------------------------------
// Kernel 1: input projection GEMM (fp32 vector ALU)
//   rows r = t*256 + b  (M = 131072), cols c in [0,384): d=c/192, g=c%192
//   xp[((d*T + t)*B + b)*192 + g] = x[b,t,:] . W_ih_d[g,:] + b_ih_d[g]
// ---------------------------------------------------------------------------
#define BM 64
#define BN 128
#define KC 12
#define NKI 25   // 300 / 12

__global__ __launch_bounds__(256) void proj_gemm(
    const float* __restrict__ x,
    const float* __restrict__ Wf, const float* __restrict__ bf,
    const float* __restrict__ Wb, const float* __restrict__ bb,
    float* __restrict__ xp)
{
    __shared__ float xs[BM][KC + 1];     // [row][kk], +1 pad breaks bank conflicts
    __shared__ float wl[KC][BN + 4];     // [kk][col], row stride 132 floats (16B-aligned)

    const int tid  = threadIdx.x;
    const int row0 = blockIdx.x * BM;
    const int c0   = blockIdx.y * BN;

    // per-thread global load pointers (constant layout, advance by KC per iter)
    const float* xptr[3];
    int xsaddr[3];
    #pragma unroll
    for (int j = 0; j < 3; ++j) {
        int q = tid + j * 256;           // [0,768)
        int lrow = q / 12, lkk = q % 12;
        int r = row0 + lrow;
        int t = r >> 8, b = r & 255;
        xptr[j]   = x + (size_t)(b * T_LEN + t) * I_SZ + lkk;
        xsaddr[j] = lrow * (KC + 1) + lkk;
    }
    const float* wptr[6];
    int wladdr[6];
    #pragma unroll
    for (int j = 0; j < 6; ++j) {
        int q = tid + j * 256;           // [0,1536)
        int lcol = q / 12, lkk = q % 12;
        int gc = c0 + lcol;
        int d = gc / G3, g = gc % G3;
        const float* W = d ? Wb : Wf;
        wptr[j]   = W + (size_t)g * I_SZ + lkk;
        wladdr[j] = lkk * (BN + 4) + lcol;
    }

    const int ty = tid >> 4, tx = tid & 15;
    float acc[4][8];
    #pragma unroll
    for (int i = 0; i < 4; ++i)
        #pragma unroll
        for (int j = 0; j < 8; ++j) acc[i][j] = 0.f;

    for (int ki = 0; ki < NKI; ++ki) {
        float xv[3], wv[6];
        #pragma unroll
        for (int j = 0; j < 3; ++j) xv[j] = *xptr[j];
        #pragma unroll
        for (int j = 0; j < 6; ++j) wv[j] = *wptr[j];
        __syncthreads();
        #pragma unroll
        for (int j = 0; j < 3; ++j) ((float*)xs)[xsaddr[j]] = xv[j];
        #pragma unroll
        for (int j = 0; j < 6; ++j) ((float*)wl)[wladdr[j]] = wv[j];
        __syncthreads();
        #pragma unroll
        for (int j = 0; j < 3; ++j) xptr[j] += KC;
        #pragma unroll
        for (int j = 0; j < 6; ++j) wptr[j] += KC;

        #pragma unroll
        for (int kk = 0; kk < KC; ++kk) {
            const float a0 = xs[ty*4+0][kk];
            const float a1 = xs[ty*4+1][kk];
            const float a2 = xs[ty*4+2][kk];
            const float a3 = xs[ty*4+3][kk];
            const float4 w0 = *(const float4*)&wl[kk][tx*8];
            const float4 w1 = *(const float4*)&wl[kk][tx*8+4];
            acc[0][0] += a0*w0.x; acc[0][1] += a0*w0.y; acc[0][2] += a0*w0.z; acc[0][3] += a0*w0.w;
            acc[0][4] += a0*w1.x; acc[0][5] += a0*w1.y; acc[0][6] += a0*w1.z; acc[0][7] += a0*w1.w;
            acc[1][0] += a1*w0.x; acc[1][1] += a1*w0.y; acc[1][2] += a1*w0.z; acc[1][3] += a1*w0.w;
            acc[1][4] += a1*w1.x; acc[1][5] += a1*w1.y; acc[1][6] += a1*w1.z; acc[1][7] += a1*w1.w;
            acc[2][0] += a2*w0.x; acc[2][1] += a2*w0.y; acc[2][2] += a2*w0.z; acc[2][3] += a2*w0.w;
            acc[2][4] += a2*w1.x; acc[2][5] += a2*w1.y; acc[2][6] += a2*w1.z; acc[2][7] += a2*w1.w;
            acc[3][0] += a3*w0.x; acc[3][1] += a3*w0.y; acc[3][2] += a3*w0.z; acc[3][3] += a3*w0.w;
            acc[3][4] += a3*w1.x; acc[3][5] += a3*w1.y; acc[3][6] += a3*w1.z; acc[3][7] += a3*w1.w;
        }
    }

    // epilogue: add bias, store (each 8-col octet stays within one direction)
    const int gc = c0 + tx * 8;
    const int dsel = gc / G3;
    const int g = gc % G3;
    const float* bias = dsel ? bb : bf;
    const float4 bi0 = *(const float4*)(bias + g);
    const float4 bi1 = *(const float4*)(bias + g + 4);
    #pragma unroll
    for (int i = 0; i < 4; ++i) {
        int r = row0 + ty * 4 + i;
        int t = r >> 8, b = r & 255;
        float* o = xp + ((size_t)(dsel * T_LEN + t) * B_SZ + b) * G3 + g;
        float4 v0 = { acc[i][0]+bi0.x, acc[i][1]+bi0.y, acc[i][2]+bi0.z, acc[i][3]+bi0.w };
        float4 v1 = { acc[i][4]+bi1.x, acc[i][5]+bi1.y, acc[i][6]+bi1.z, acc[i][7]+bi1.w };
        *(float4*)o       = v0;
        *(float4*)(o + 4) = v1;
    }
}

// ---------------------------------------------------------------------------
// Kernel 2: GRU recurrent scan. 512 blocks = 2 dirs x 256 batches.
// 192 threads: thread g owns gate g (W_hh row in 64 VGPRs).
// Only first-step and final hidden states are needed -> feat[b][256].
// ---------------------------------------------------------------------------
__device__ __forceinline__ float sigm_f(float x) {
    return __builtin_amdgcn_rcpf(1.f + __expf(-x));
}
__device__ __forceinline__ float tanh_f(float x) {
    float a = fabsf(x);
    float e = __expf(2.f * a);                       // inf ok: rcp(inf)=0
    float t = 1.f - 2.f * __builtin_amdgcn_rcpf(1.f + e);
    return copysignf(t, x);
}

__global__ __launch_bounds__(192) void gru_scan(
    const float* __restrict__ xp,
    const float* __restrict__ Whf, const float* __restrict__ bhf,
    const float* __restrict__ Whb, const float* __restrict__ bhb,
    float* __restrict__ feat)
{
    const int g   = threadIdx.x;       // 0..191
    const int bid = blockIdx.x;        // 0..511
    const int d   = bid >> 8;
    const int b   = bid & 255;

    const float* Whh = d ? Whb : Whf;
    const float* bhh = d ? bhb : bhf;

    float4 w[16];
    #pragma unroll
    for (int k = 0; k < 16; ++k) w[k] = *(const float4*)(Whh + g * 64 + k * 4);
    const float bh = bhh[g];

    __shared__ float h_s[64];
    __shared__ float gh_s[192];
    if (g < 64) h_s[g] = 0.f;
    float hreg = 0.f;

    const long step = d ? -(long)(B_SZ * G3) : (long)(B_SZ * G3);
    const float* xb = xp + ((size_t)(d * T_LEN + (d ? T_LEN - 1 : 0)) * B_SZ + b) * G3;
    float xr = 0.f, xz = 0.f, xn = 0.f, xr_n = 0.f, xz_n = 0.f, xn_n = 0.f;
    if (g < 64) { xr = xb[g]; xz = xb[64 + g]; xn = xb[128 + g]; }
    __syncthreads();

    for (int s = 0; s < T_LEN; ++s) {
        // phase 1: gh[g] = b_hh[g] + W_hh[g,:] . h   (h broadcast from LDS)
        float a = bh;
        const float4* h4 = (const float4*)h_s;
        #pragma unroll
        for (int k = 0; k < 16; ++k) {
            float4 hv = h4[k];
            a += w[k].x * hv.x + w[k].y * hv.y + w[k].z * hv.z + w[k].w * hv.w;
        }
        // prefetch next step's xp
        if (g < 64 && s + 1 < T_LEN) {
            const float* xnb = xb + step;
            xr_n = xnb[g]; xz_n = xnb[64 + g]; xn_n = xnb[128 + g];
        }
        gh_s[g] = a;
        __syncthreads();

        // phase 2: pointwise update (threads 0..63)
        if (g < 64) {
            float r = sigm_f(xr + gh_s[g]);
            float z = sigm_f(xz + gh_s[64 + g]);
            float n = tanh_f(xn + r * gh_s[128 + g]);
            hreg = (1.f - z) * n + z * hreg;
            h_s[g] = hreg;
            if (s == 0)         feat[b * 256 + (d ? 192 : 0) + g] = hreg;
            if (s == T_LEN - 1) feat[b * 256 + (d ? 64 : 128) + g] = hreg;
            xr = xr_n; xz = xz_n; xn = xn_n;
        }
        xb += step;
        __syncthreads();
    }
}

// ---------------------------------------------------------------------------
// Kernel 3: MLP head. feat[b][256] -> 32 (LeakyReLU) -> 1
// ---------------------------------------------------------------------------
__global__ __launch_bounds__(64) void head_k(
    const float* __restrict__ feat,
    const float* __restrict__ W1, const float* __restrict__ b1,
    const float* __restrict__ W2, const float* __restrict__ b2,
    float* __restrict__ out)
{
    __shared__ float fs[256];
    const int b = blockIdx.x;
    const int tid = threadIdx.x;
    *(float4*)&fs[tid * 4] = *(const float4*)&feat[b * 256 + tid * 4];
    __syncthreads();
    float v = 0.f;
    if (tid < 32) {
        float a = b1[tid];
        const float4* Wv = (const float4*)(W1 + tid * 256);
        const float4* fv = (const float4*)fs;
        #pragma unroll 8
        for (int k = 0; k < 64; ++k) {
            float4 w = Wv[k], f = fv[k];
            a += w.x * f.x + w.y * f.y + w.z * f.z + w.w * f.w;
        }
        a = a >= 0.f ? a : 0.01f * a;
        v = a * W2[tid];
    }
    #pragma unroll
    for (int off = 16; off > 0; off >>= 1) v += __shfl_down(v, off);
    if (tid == 0) out[b] = v + b2[0];
}

// ---------------------------------------------------------------------------
extern "C" void kernel_launch(void* const* d_in, const int* in_sizes, int n_in,
                              void* d_out, int out_size, void* d_ws, size_t ws_size,
                              hipStream_t stream)
{
    const float* x    = (const float*)d_in[0];
    const float* Wihf = (const float*)d_in[1];
    const float* Whhf = (const float*)d_in[2];
    const float* bihf = (const float*)d_in[3];
    const float* bhhf = (const float*)d_in[4];
    const float* Wihb = (const float*)d_in[5];
    const float* Whhb = (const float*)d_in[6];
    const float* bihb = (const float*)d_in[7];
    const float* bhhb = (const float*)d_in[8];
    const float* W1   = (const float*)d_in[9];
    const float* b1   = (const float*)d_in[10];
    const float* W2   = (const float*)d_in[11];
    const float* b2   = (const float*)d_in[12];
    float* out = (float*)d_out;

    float* xp   = (float*)d_ws;                              // 2*512*256*192 fp32
    float* feat = xp + (size_t)2 * T_LEN * B_SZ * G3;        // 256*256 fp32

    dim3 gg(131072 / BM, 384 / BN);   // (2048, 3)
    proj_gemm<<<gg, 256, 0, stream>>>(x, Wihf, bihf, Wihb, bihb, xp);
    gru_scan<<<512, 192, 0, stream>>>(xp, Whhf, bhhf, Whhb, bhhb, feat);
    head_k<<<256, 64, 0, stream>>>(feat, W1, b1, W2, b2, out);
}

// Round 2
// 711.237 us; speedup vs baseline: 1.3597x; 1.3597x over previous
//
#include <hip/hip_runtime.h>
#include <hip/hip_bf16.h>
#include <math.h>

#define T_LEN 512
#define B_SZ  256
#define I_SZ  300
#define H_SZ  64
#define G3    192   // 3H

typedef float f4v   __attribute__((ext_vector_type(4)));
typedef short s8v   __attribute__((ext_vector_type(8)));

// split fp32 -> hi bf16 + lo bf16 (residual), both round-to-nearest-even
__device__ __forceinline__ void split_bf16(float x, unsigned short& hi, unsigned short& lo) {
    unsigned u = __builtin_bit_cast(unsigned, x);
    unsigned h = (u + 0x7FFFu + ((u >> 16) & 1u)) >> 16;
    hi = (unsigned short)h;
    float hf = __builtin_bit_cast(float, h << 16);
    float l = x - hf;
    unsigned ul = __builtin_bit_cast(unsigned, l);
    lo = (unsigned short)((ul + 0x7FFFu + ((ul >> 16) & 1u)) >> 16);
}

// ---------------------------------------------------------------------------
// Kernel 1: input projection via split-bf16 MFMA.
//   C[m=(t,b)][n=(d,g)] = X[m][k] . W[n][k] + bias[n]
//   BM=128 (one t, 128 b's), BN=192 (one direction), K = 10 chunks of 32.
//   3-term product: hi*hi + hi*lo + lo*hi  (error ~2^-18, fp32-like)
// ---------------------------------------------------------------------------
#define NKC 10

__global__ __launch_bounds__(256) void proj_gemm(
    const float* __restrict__ x,
    const float* __restrict__ Wf, const float* __restrict__ bf,
    const float* __restrict__ Wb, const float* __restrict__ bb,
    float* __restrict__ xp)
{
    __shared__ unsigned short Ahi[128 * 32];
    __shared__ unsigned short Alo[128 * 32];
    __shared__ unsigned short Bhi[192 * 32];
    __shared__ unsigned short Blo[192 * 32];

    const int tid = threadIdx.x;
    const int d   = blockIdx.x;            // 0..1 direction (N-block)
    const int m0  = blockIdx.y * 128;      // row block
    const int t_blk = m0 >> 8;             // fixed t for this block
    const int b0    = m0 & 255;            // 0 or 128

    const float* W    = d ? Wb : Wf;
    const float* bias = d ? bb : bf;

    // staging thread mapping: 32 rows per pass, 8 float4 per row
    const int srow = tid >> 3;             // 0..31
    const int sq   = tid & 7;              // float4 index in row (k = sq*4)

    // MFMA lane mapping
    const int lane = tid & 63;
    const int w    = tid >> 6;             // wave 0..3
    const int wm   = (w & 1) * 64;         // wave M offset (0/64)
    const int wn   = (w >> 1) * 96;        // wave N offset (0/96)
    const int frow = lane & 15;
    const int kq   = lane >> 4;

    f4v acc[4][6];
    #pragma unroll
    for (int mt = 0; mt < 4; ++mt)
        #pragma unroll
        for (int nt = 0; nt < 6; ++nt) acc[mt][nt] = (f4v)0.f;

    for (int kc = 0; kc < NKC; ++kc) {
        const int k0 = kc * 32;
        const bool valid = (k0 + sq * 4) < 297;   // last chunk: only 12 of 32 k valid

        // ---- global loads (A: 4 passes of 32 rows; B: 6 passes) ----
        float4 av[4], bv[6];
        #pragma unroll
        for (int p = 0; p < 4; ++p) {
            int row = p * 32 + srow;              // 0..127 -> b = b0+row
            const float* gp = x + (size_t)((b0 + row) * T_LEN + t_blk) * I_SZ + k0 + sq * 4;
            av[p] = valid ? *(const float4*)gp : float4{0.f, 0.f, 0.f, 0.f};
        }
        #pragma unroll
        for (int p = 0; p < 6; ++p) {
            int row = p * 32 + srow;              // 0..191 -> g = row
            const float* gp = W + (size_t)row * I_SZ + k0 + sq * 4;
            bv[p] = valid ? *(const float4*)gp : float4{0.f, 0.f, 0.f, 0.f};
        }

        __syncthreads();   // previous chunk's fragment reads done

        // ---- convert + LDS write ----
        #pragma unroll
        for (int p = 0; p < 4; ++p) {
            int row = p * 32 + srow;
            ushort4 h4, l4;
            split_bf16(av[p].x, h4.x, l4.x); split_bf16(av[p].y, h4.y, l4.y);
            split_bf16(av[p].z, h4.z, l4.z); split_bf16(av[p].w, h4.w, l4.w);
            *(ushort4*)&Ahi[row * 32 + sq * 4] = h4;
            *(ushort4*)&Alo[row * 32 + sq * 4] = l4;
        }
        #pragma unroll
        for (int p = 0; p < 6; ++p) {
            int row = p * 32 + srow;
            ushort4 h4, l4;
            split_bf16(bv[p].x, h4.x, l4.x); split_bf16(bv[p].y, h4.y, l4.y);
            split_bf16(bv[p].z, h4.z, l4.z); split_bf16(bv[p].w, h4.w, l4.w);
            *(ushort4*)&Bhi[row * 32 + sq * 4] = h4;
            *(ushort4*)&Blo[row * 32 + sq * 4] = l4;
        }
        __syncthreads();

        // ---- fragment loads + MFMA ----
        s8v bh_[6], bl_[6];
        #pragma unroll
        for (int nt = 0; nt < 6; ++nt) {
            int off = (wn + nt * 16 + frow) * 32 + kq * 8;
            bh_[nt] = *(const s8v*)&Bhi[off];
            bl_[nt] = *(const s8v*)&Blo[off];
        }
        #pragma unroll
        for (int mt = 0; mt < 4; ++mt) {
            int off = (wm + mt * 16 + frow) * 32 + kq * 8;
            s8v ah = *(const s8v*)&Ahi[off];
            s8v al = *(const s8v*)&Alo[off];
            #pragma unroll
            for (int nt = 0; nt < 6; ++nt) {
                acc[mt][nt] = __builtin_amdgcn_mfma_f32_16x16x32_bf16(al, bh_[nt], acc[mt][nt], 0, 0, 0);
                acc[mt][nt] = __builtin_amdgcn_mfma_f32_16x16x32_bf16(ah, bl_[nt], acc[mt][nt], 0, 0, 0);
                acc[mt][nt] = __builtin_amdgcn_mfma_f32_16x16x32_bf16(ah, bh_[nt], acc[mt][nt], 0, 0, 0);
            }
        }
    }

    // ---- epilogue: bias + store to xp[((d*T + t)*B + b)*192 + g] ----
    const int col  = lane & 15;
    const int rowq = lane >> 4;
    float bias_v[6];
    #pragma unroll
    for (int nt = 0; nt < 6; ++nt) bias_v[nt] = bias[wn + nt * 16 + col];

    #pragma unroll
    for (int mt = 0; mt < 4; ++mt) {
        #pragma unroll
        for (int reg = 0; reg < 4; ++reg) {
            int b = b0 + wm + mt * 16 + rowq * 4 + reg;
            float* o = xp + ((size_t)(d * T_LEN + t_blk) * B_SZ + b) * G3;
            #pragma unroll
            for (int nt = 0; nt < 6; ++nt) {
                int g = wn + nt * 16 + col;
                o[g] = acc[mt][nt][reg] + bias_v[nt];
            }
        }
    }
}

// ---------------------------------------------------------------------------
// Kernel 2: GRU scan, 512 blocks (2 dir x 256 batch), 192 threads.
// xp staged through a double-buffered LDS ring, 16 steps (12 KB) per chunk,
// so the barrier vmcnt-drain cost is paid once per 16 steps, not every step.
// ---------------------------------------------------------------------------
#define CH 16
#define NCHUNK 32   // 512 / 16

__device__ __forceinline__ float sigm_f(float x) {
    return __builtin_amdgcn_rcpf(1.f + __expf(-x));
}
__device__ __forceinline__ float tanh_f(float x) {
    float a = fabsf(x);
    float e = __expf(2.f * a);
    float t = 1.f - 2.f * __builtin_amdgcn_rcpf(1.f + e);
    return copysignf(t, x);
}

__global__ __launch_bounds__(192) void gru_scan(
    const float* __restrict__ xp,
    const float* __restrict__ Whf, const float* __restrict__ bhf,
    const float* __restrict__ Whb, const float* __restrict__ bhb,
    float* __restrict__ feat)
{
    const int g   = threadIdx.x;       // 0..191
    const int bid = blockIdx.x;        // 0..511
    const int d   = bid >> 8;
    const int b   = bid & 255;

    const float* Whh = d ? Whb : Whf;
    const float* bhh = d ? bhb : bhf;

    float4 w[16];
    #pragma unroll
    for (int k = 0; k < 16; ++k) w[k] = *(const float4*)(Whh + g * 64 + k * 4);
    const float bh = bhh[g];

    __shared__ __align__(16) float sbuf[2][CH][G3];   // 24 KB xp ring
    __shared__ __align__(16) float h_s[64];
    __shared__ float gh_s[G3];

    const long sstep = d ? -(long)(B_SZ * G3) : (long)(B_SZ * G3);
    const float* xb0 = xp + ((size_t)(d ? (T_LEN + T_LEN - 1) : 0) * B_SZ + b) * G3;

    // chunk-load mapping: 768 float4 per chunk / 192 threads = 4 each
    const int lq = g % 48;     // float4 within step (k = lq*4)
    const int ls = g / 48;     // 0..3 -> steps ls, 4+ls, 8+ls, 12+ls

    float4 pf[4];
    #pragma unroll
    for (int j = 0; j < 4; ++j)
        pf[j] = *(const float4*)(xb0 + (long)(j * 4 + ls) * sstep + lq * 4);
    #pragma unroll
    for (int j = 0; j < 4; ++j)
        *(float4*)&sbuf[0][j * 4 + ls][lq * 4] = pf[j];

    if (g < 64) h_s[g] = 0.f;
    float hreg = 0.f;
    __syncthreads();

    for (int c = 0; c < NCHUNK; ++c) {
        const int cur = c & 1;
        if (c + 1 < NCHUNK) {
            const long gb = (long)(c + 1) * CH;
            #pragma unroll
            for (int j = 0; j < 4; ++j)
                pf[j] = *(const float4*)(xb0 + (gb + j * 4 + ls) * sstep + lq * 4);
        }
        for (int s2 = 0; s2 < CH; ++s2) {
            // phase 1: gh[g] = b_hh[g] + W_hh[g,:] . h   (4 partial sums)
            float a0 = bh, a1 = 0.f, a2 = 0.f, a3 = 0.f;
            const float4* h4 = (const float4*)h_s;
            #pragma unroll
            for (int k = 0; k < 16; k += 4) {
                float4 h0 = h4[k], h1 = h4[k + 1], h2 = h4[k + 2], h3 = h4[k + 3];
                a0 = fmaf(w[k].x, h0.x, a0); a0 = fmaf(w[k].y, h0.y, a0);
                a0 = fmaf(w[k].z, h0.z, a0); a0 = fmaf(w[k].w, h0.w, a0);
                a1 = fmaf(w[k+1].x, h1.x, a1); a1 = fmaf(w[k+1].y, h1.y, a1);
                a1 = fmaf(w[k+1].z, h1.z, a1); a1 = fmaf(w[k+1].w, h1.w, a1);
                a2 = fmaf(w[k+2].x, h2.x, a2); a2 = fmaf(w[k+2].y, h2.y, a2);
                a2 = fmaf(w[k+2].z, h2.z, a2); a2 = fmaf(w[k+2].w, h2.w, a2);
                a3 = fmaf(w[k+3].x, h3.x, a3); a3 = fmaf(w[k+3].y, h3.y, a3);
                a3 = fmaf(w[k+3].z, h3.z, a3); a3 = fmaf(w[k+3].w, h3.w, a3);
            }
            gh_s[g] = (a0 + a1) + (a2 + a3);
            __syncthreads();

            // phase 2: pointwise update (threads 0..63)
            if (g < 64) {
                float xr = sbuf[cur][s2][g];
                float xz = sbuf[cur][s2][64 + g];
                float xn = sbuf[cur][s2][128 + g];
                float r = sigm_f(xr + gh_s[g]);
                float z = sigm_f(xz + gh_s[64 + g]);
                float n = tanh_f(xn + r * gh_s[128 + g]);
                hreg = (1.f - z) * n + z * hreg;
                h_s[g] = hreg;
                if (c == 0 && s2 == 0)
                    feat[b * 256 + (d ? 192 : 0) + g] = hreg;
                if (c == NCHUNK - 1 && s2 == CH - 1)
                    feat[b * 256 + (d ? 64 : 128) + g] = hreg;
            }
            __syncthreads();
        }
        if (c + 1 < NCHUNK) {
            #pragma unroll
            for (int j = 0; j < 4; ++j)
                *(float4*)&sbuf[cur ^ 1][j * 4 + ls][lq * 4] = pf[j];
        }
        __syncthreads();
    }
}

// ---------------------------------------------------------------------------
// Kernel 3: MLP head. feat[b][256] -> 32 (LeakyReLU) -> 1
// ---------------------------------------------------------------------------
__global__ __launch_bounds__(64) void head_k(
    const float* __restrict__ feat,
    const float* __restrict__ W1, const float* __restrict__ b1,
    const float* __restrict__ W2, const float* __restrict__ b2,
    float* __restrict__ out)
{
    __shared__ float fs[256];
    const int b = blockIdx.x;
    const int tid = threadIdx.x;
    *(float4*)&fs[tid * 4] = *(const float4*)&feat[b * 256 + tid * 4];
    __syncthreads();
    float v = 0.f;
    if (tid < 32) {
        float a = b1[tid];
        const float4* Wv = (const float4*)(W1 + tid * 256);
        const float4* fv = (const float4*)fs;
        #pragma unroll 8
        for (int k = 0; k < 64; ++k) {
            float4 wv = Wv[k], f = fv[k];
            a += wv.x * f.x + wv.y * f.y + wv.z * f.z + wv.w * f.w;
        }
        a = a >= 0.f ? a : 0.01f * a;
        v = a * W2[tid];
    }
    #pragma unroll
    for (int off = 16; off > 0; off >>= 1) v += __shfl_down(v, off);
    if (tid == 0) out[b] = v + b2[0];
}

// ---------------------------------------------------------------------------
extern "C" void kernel_launch(void* const* d_in, const int* in_sizes, int n_in,
                              void* d_out, int out_size, void* d_ws, size_t ws_size,
                              hipStream_t stream)
{
    const float* x    = (const float*)d_in[0];
    const float* Wihf = (const float*)d_in[1];
    const float* Whhf = (const float*)d_in[2];
    const float* bihf = (const float*)d_in[3];
    const float* bhhf = (const float*)d_in[4];
    const float* Wihb = (const float*)d_in[5];
    const float* Whhb = (const float*)d_in[6];
    const float* bihb = (const float*)d_in[7];
    const float* bhhb = (const float*)d_in[8];
    const float* W1   = (const float*)d_in[9];
    const float* b1   = (const float*)d_in[10];
    const float* W2   = (const float*)d_in[11];
    const float* b2   = (const float*)d_in[12];
    float* out = (float*)d_out;

    float* xp   = (float*)d_ws;                              // 2*512*256*192 fp32
    float* feat = xp + (size_t)2 * T_LEN * B_SZ * G3;        // 256*256 fp32

    dim3 gg(2, 1024);   // x = direction (N-block), y = row block; x fastest for L2 reuse of X
    proj_gemm<<<gg, 256, 0, stream>>>(x, Wihf, bihf, Wihb, bihb, xp);
    gru_scan<<<512, 192, 0, stream>>>(xp, Whhf, bhhf, Whhb, bhhb, feat);
    head_k<<<256, 64, 0, stream>>>(feat, W1, b1, W2, b2, out);
}